// Round 8
// baseline (866.566 us; speedup 1.0000x reference)
//
#include <hip/hip_runtime.h>
#include <math.h>

// SSIM loss, fused separable implementation, round 8 (= r7 with NaN fix).
// Algebra: s=x+y, d=x-y; 4 separable Gaussian convs (s, d, s^2, d^2):
//   2*mu1mu2 = (mp^2-mm^2)/2 ; mu1^2+mu2^2 = (mp^2+mm^2)/2
//   2*s12    = (varP-varM)/2 ; s11+s22    = (varP+varM)/2
// r7 bug: __builtin_amdgcn_readfirstlane(float) did an implicit float->int
// VALUE conversion (0.043 -> 0 -> 1/sqrt(0)=inf -> NaN). Fixed with a
// bit-cast wrapper. Experiment unchanged:
//  - Target VGPR = 64 with no spill -> 2 blocks/CU (only r2, at VGPR 64,
//    ever showed 39.6% occupancy; all 72+ rounds sat at 21%).
//  - va[14] deleted (inline address recompute), weights in SGPRs, int32
//    global offsets, __launch_bounds__(512,4) = 64-VGPR cap (r2 evidence).
//  - Plain scalar math (r6: packed fp32 is issue-compression only on CDNA4).

#define HH 512
#define WW 512
#define NPLANES 96   // 32*3
#define ROWS 64      // output rows per block
#define CH 4         // chunk rows per barrier period
#define NCHUNK 16
#define LSTRIDE 528  // f32x4 slots per row: 8 zero-guard + 512 + 8 zero-guard
#define NT 512

#define C1F 0.0001f  // 0.01^2
#define C2F 0.0009f  // 0.03^2

typedef float f32x2 __attribute__((ext_vector_type(2)));
typedef float f32x4 __attribute__((ext_vector_type(4)));

__device__ __forceinline__ int swz(int c) { return c ^ ((c >> 5) & 31); }

// readfirstlane for float: BIT-cast, not value-cast (r7 NaN bug)
__device__ __forceinline__ float rfl_f32(float x) {
  return __int_as_float(__builtin_amdgcn_readfirstlane(__float_as_int(x)));
}

extern "C" __global__ __launch_bounds__(NT, 4)
void ssim_main(const float* __restrict__ Ii, const float* __restrict__ Ir,
               const float* __restrict__ win, float* __restrict__ partial) {
  __shared__ f32x4 vbuf[CH * LSTRIDE];   // 4*528*16B = 33792 B
  __shared__ float psum[8];

  const int tid = threadIdx.x;
  const int b = blockIdx.x;
  const int plane = b >> 3;
  const int r0 = (b & 7) * ROWS;

  // 1-D gaussian from the 2-D window; force into SGPRs (wave-uniform).
  float g[11];
  {
    const float gi = 1.0f / sqrtf(rfl_f32(win[55 + 5]));
#pragma unroll
    for (int j = 0; j < 11; ++j)
      g[j] = rfl_f32(win[55 + j]) * gi;
  }

  // int32 offsets -> SGPR-base + voffset global addressing (fewer VGPRs)
  const int pbase = plane * (HH * WW) + tid;
  const int wb = 8 + swz(tid);    // swizzled LDS write slot

  // zero the guard slots once (4 rows * 16 slots = 64); never overwritten
  if (tid < 64) {
    const int lr = tid >> 4, p = tid & 15;
    f32x4 z; z.x = 0.f; z.y = 0.f; z.z = 0.f; z.w = 0.f;
    vbuf[lr * LSTRIDE + (p < 8 ? p : 512 + p)] = z;
  }

  // mod-11 ring accumulators, packed pairs: r1=(S,D), r2=(P,M)
  f32x2 r1[11], r2[11];
  float pfA[CH], pfB[CH];
  float sum = 0.f;

  auto loadrow = [&](int u, float& a, float& bb) {
    const int r = r0 - 5 + u;
    const int rc = min(max(r, 0), HH - 1);
    const int off = pbase + rc * WW;
    float ta = Ii[off];
    float tb = Ir[off];
    const bool ok = (unsigned)r < (unsigned)HH;
    a = ok ? ta : 0.f;
    bb = ok ? tb : 0.f;
  };

  // vertical step for input local row u (compile-time); emit to lr when lr>=0
  auto vrow = [&](int u, float a, float bb, int lr) {
    f32x2 sd; sd.x = a + bb; sd.y = a - bb;
    f32x2 pm; pm.x = sd.x * sd.x; pm.y = sd.y * sd.y;
    {
      const int sl = u % 11;
      r1[sl].x = g[0] * sd.x; r1[sl].y = g[0] * sd.y;
      r2[sl].x = g[0] * pm.x; r2[sl].y = g[0] * pm.y;
    }
#pragma unroll
    for (int t = 1; t < 11; ++t) {
      const int sl = (u + 44 - t) % 11;
      r1[sl].x = fmaf(g[t], sd.x, r1[sl].x);
      r1[sl].y = fmaf(g[t], sd.y, r1[sl].y);
      r2[sl].x = fmaf(g[t], pm.x, r2[sl].x);
      r2[sl].y = fmaf(g[t], pm.y, r2[sl].y);
    }
    if (lr >= 0) {
      const int sl = (u + 1) % 11;     // (u-10) mod 11
      f32x4 o;
      o.x = r1[sl].x; o.y = r1[sl].y; o.z = r2[sl].x; o.w = r2[sl].y;
      vbuf[lr * LSTRIDE + wb] = o;
    }
  };

  // horizontal conv + SSIM; addresses recomputed inline (no va[] array)
  auto hchunk = [&]() {
    f32x2 h01[4], h23[4];
    const int rb8 = (tid >> 7) * LSTRIDE + 8;   // wave-uniform row base (+guard)
    const int c0 = (tid & 127) * 4;             // 4 contiguous output cols
#pragma unroll
    for (int j = 0; j < 14; ++j) {
      const int col = c0 + j - 5;
      const int ad = rb8 + (((unsigned)col > 511u) ? col : swz(col));
      const f32x4 v = vbuf[ad];
      const int clo = (j - 10 > 0) ? (j - 10) : 0;
      const int chi = (j < 3) ? j : 3;
#pragma unroll
      for (int c = clo; c <= chi; ++c) {
        const float w = g[j - c];
        if (c == j) {
          h01[c].x = w * v.x; h01[c].y = w * v.y;
          h23[c].x = w * v.z; h23[c].y = w * v.w;
        } else {
          h01[c].x = fmaf(w, v.x, h01[c].x);
          h01[c].y = fmaf(w, v.y, h01[c].y);
          h23[c].x = fmaf(w, v.z, h23[c].x);
          h23[c].y = fmaf(w, v.w, h23[c].y);
        }
      }
    }
#pragma unroll
    for (int c = 0; c < 4; ++c) {
      const float mp2 = h01[c].x * h01[c].x;
      const float mm2 = h01[c].y * h01[c].y;
      const float varP = h23[c].x - mp2;
      const float varM = h23[c].y - mm2;
      const float num1 = 0.5f * (mp2 - mm2) + C1F;
      const float den1 = 0.5f * (mp2 + mm2) + C1F;
      const float num2 = 0.5f * (varP - varM) + C2F;
      const float den2 = 0.5f * (varP + varM) + C2F;
      sum += __fdividef(num1 * num2, den1 * den2);
    }
  };

  // prologue: ring fill (u=0..9), prefetch chunk 0 (u=10..13)
#pragma unroll
  for (int u = 0; u < 10; ++u) {
    float a, bb; loadrow(u, a, bb); vrow(u, a, bb, -1);
  }
#pragma unroll
  for (int i = 0; i < CH; ++i) loadrow(10 + i, pfA[i], pfB[i]);

  // main loop: V(c) writes | prefetch(c+1) | bar | H(c) reads | bar
#pragma unroll
  for (int c = 0; c < NCHUNK; ++c) {
#pragma unroll
    for (int i = 0; i < CH; ++i) vrow(10 + 4 * c + i, pfA[i], pfB[i], i);
    if (c < NCHUNK - 1) {
#pragma unroll
      for (int i = 0; i < CH; ++i) loadrow(14 + 4 * c + i, pfA[i], pfB[i]);
    }
    asm volatile("s_waitcnt lgkmcnt(0)" ::: "memory");  // LDS writes visible
    __builtin_amdgcn_s_barrier();
    hchunk();
    if (c < NCHUNK - 1) {
      asm volatile("s_waitcnt lgkmcnt(0)" ::: "memory"); // LDS reads done
      __builtin_amdgcn_s_barrier();                      // before next V writes
    }
  }

  // deterministic block reduction
#pragma unroll
  for (int off = 32; off > 0; off >>= 1) sum += __shfl_down(sum, off, 64);
  if ((tid & 63) == 0) psum[tid >> 6] = sum;
  __syncthreads();
  if (tid == 0) {
    float t = 0.f;
#pragma unroll
    for (int wv = 0; wv < 8; ++wv) t += psum[wv];
    partial[b] = t;
  }
}

extern "C" __global__ void ssim_reduce(const float* __restrict__ partial,
                                       float* __restrict__ out, int n, float scale) {
  __shared__ float sm[4];
  const int tid = threadIdx.x;
  float v = 0.f;
  for (int i = tid; i < n; i += 256) v += partial[i];
#pragma unroll
  for (int off = 32; off > 0; off >>= 1) v += __shfl_down(v, off, 64);
  if ((tid & 63) == 0) sm[tid >> 6] = v;
  __syncthreads();
  if (tid == 0) {
    out[0] = 1.0f - (sm[0] + sm[1] + sm[2] + sm[3]) * scale;
  }
}

extern "C" void kernel_launch(void* const* d_in, const int* in_sizes, int n_in,
                              void* d_out, int out_size, void* d_ws, size_t ws_size,
                              hipStream_t stream) {
  const float* Ii = (const float*)d_in[0];
  const float* Ir = (const float*)d_in[1];
  const float* win = (const float*)d_in[2];
  float* out = (float*)d_out;
  float* partial = (float*)d_ws;   // 768 floats

  const int nblocks = NPLANES * 8;  // 768
  ssim_main<<<dim3(nblocks), dim3(NT), 0, stream>>>(Ii, Ir, win, partial);
  ssim_reduce<<<dim3(1), dim3(256), 0, stream>>>(partial, out, nblocks,
                                                 1.0f / 25165824.0f);
}

// Round 10
// 174.405 us; speedup vs baseline: 4.9687x; 4.9687x over previous
//
#include <hip/hip_runtime.h>
#include <math.h>

// SSIM loss, round 10 (= round 9 resubmit; r9 died to an infra error).
// MFMA-based separable convolution.
// s=x+y, d=x-y; 4 Gaussian convs (s, d, s^2, d^2) give the SSIM map:
//   2*mu1mu2 = (mp^2-mm^2)/2 ; mu1^2+mu2^2 = (mp^2+mm^2)/2
//   2*s12    = (varP-varM)/2 ; s11+s22    = (varP+varM)/2
// 11-tap conv as banded matmul on matrix cores (f16 in, f32 acc):
//   const band fragment B[k][j] = g[k-j] (0<=k-j<=10) serves BOTH passes.
//   vertical:  D[c][rho] = sum_k Qt[c][k] * g[k-rho]   (Qt = transposed s/d tile)
//   horizontal:D[r][j]   = sum_k V[r][k]  * g[k-j]
// Layout-robustness: both A and B fragments are built by US with the same
// k-labeling kappa(g,e)=8g+e (g=lane>>4, e=elem). MFMA pairs A(g,e) with
// B(g,e) regardless of the hardware's internal k interpretation, so the
// conv sum is correct under ANY true k-mapping. Hardware-measured layouts
// relied on: C/D col=lane&15, row=4*(lane>>4)+m (m89, dtype-independent);
// A-row/B-col = lane&15 (standard 16x16).
// Block = 256 thr (4 waves), 64x64 output tile. Wave w owns out rows
// w*16..+15: writes V rows w*16.. and reads only those back -> no barrier
// between passes (per-wave DS ordering). s^2/d^2 fragments built in-register
// (v_pk_mul_f16) from the s/d fragments -- halves LDS staging.
// r8 lesson: no launch_bounds VGPR cap (spill storm).

#define HH 512
#define WW 512
#define C1F 0.0001f  // 0.01^2
#define C2F 0.0009f  // 0.03^2
#define QPAD 88      // row pitch in halfs: 176B = 44 banks -> bounded conflicts,
                     // and multiples of 4 halfs keep b64/b128 alignment
#define NT 256

typedef _Float16 half8 __attribute__((ext_vector_type(8)));
typedef _Float16 half4v __attribute__((ext_vector_type(4)));
typedef float f32x4 __attribute__((ext_vector_type(4)));

extern "C" __global__ __launch_bounds__(NT)
void ssim_main(const float* __restrict__ Ii, const float* __restrict__ Ir,
               const float* __restrict__ win, float* __restrict__ partial) {
  __shared__ _Float16 QtS[80 * QPAD];      // transposed [col][row] s tile
  __shared__ _Float16 QtD[80 * QPAD];      // transposed [col][row] d tile
  __shared__ _Float16 VS[64 * QPAD];       // vertical conv outputs, row-major
  __shared__ _Float16 VD[64 * QPAD];
  __shared__ _Float16 VP[64 * QPAD];
  __shared__ _Float16 VM[64 * QPAD];
  __shared__ float psum[4];

  const int tid = threadIdx.x;
  const int b = blockIdx.x;
  const int plane = b >> 6;
  const int t6 = b & 63;
  const int r0 = (t6 >> 3) * 64;
  const int c0 = (t6 & 7) * 64;

  // 1-D gaussian from the 2-D window: g[j] = w2d[5][j]/sqrt(w2d[5][5])
  float g[11];
  {
    const float gi = 1.0f / sqrtf(win[55 + 5]);
#pragma unroll
    for (int j = 0; j < 11; ++j) g[j] = win[55 + j] * gi;
  }

  const int lane = tid & 63;
  const int li = lane & 15;
  const int ch = lane >> 4;

  // constant band fragment (B-operand, both passes): B[k][li] = g[k-li],
  // k = kappa(ch,e) = ch*8+e (our labeling; see header comment)
  half8 band;
#pragma unroll
  for (int e = 0; e < 8; ++e) {
    const int k = ch * 8 + e;
    const int tt = k - li;
    band[e] = (tt >= 0 && tt <= 10) ? (_Float16)g[tt] : (_Float16)0.0f;
  }

  // ---- stage 80x80 region (input rows/cols r0-5.., zero outside image) ----
  {
    const int grp = tid / 80;            // 0..2 active, grp 3 (16 thr) idle
    const int col = tid - grp * 80;
    if (grp < 3) {
      const int gc = c0 - 5 + col;
      const bool cok = (unsigned)gc < (unsigned)WW;
      const int gcc = min(max(gc, 0), WW - 1);
      const int pb = plane * (HH * WW) + gcc;
#pragma unroll 9
      for (int rr = 0; rr < 27; ++rr) {
        const int row = grp * 27 + rr;
        if (row < 80) {
          const int gr = r0 - 5 + row;
          const bool ok = cok && ((unsigned)gr < (unsigned)HH);
          const int grc = min(max(gr, 0), HH - 1);
          const float a = Ii[pb + grc * WW];
          const float bb = Ir[pb + grc * WW];
          const float s = ok ? (a + bb) : 0.f;
          const float d = ok ? (a - bb) : 0.f;
          QtS[col * QPAD + row] = (_Float16)s;
          QtD[col * QPAD + row] = (_Float16)d;
        }
      }
    }
  }
  __syncthreads();

  const int w = tid >> 6;                // wave id == output row-tile
  const f32x4 z4 = {0.f, 0.f, 0.f, 0.f};

  // ---- vertical pass: wave w computes V rows w*16..w*16+15, all 80 cols ----
#pragma unroll
  for (int ct = 0; ct < 5; ++ct) {
    const int ra = (ct * 16 + li) * QPAD + w * 16 + ch * 8;  // A: row=li(col of Qt), k-run
    const half8 fS = *(const half8*)&QtS[ra];
    const half8 fD = *(const half8*)&QtD[ra];
    const half8 fP = fS * fS;            // v_pk_mul_f16: squares in-register
    const half8 fM = fD * fD;
    f32x4 aS = __builtin_amdgcn_mfma_f32_16x16x32_f16(fS, band, z4, 0, 0, 0);
    f32x4 aD = __builtin_amdgcn_mfma_f32_16x16x32_f16(fD, band, z4, 0, 0, 0);
    f32x4 aP = __builtin_amdgcn_mfma_f32_16x16x32_f16(fP, band, z4, 0, 0, 0);
    f32x4 aM = __builtin_amdgcn_mfma_f32_16x16x32_f16(fM, band, z4, 0, 0, 0);
    // D[c][rho]: lane holds rho=li, c = ch*4+m -> 4 contiguous V cols, 1 b64 write
    const int wa = (w * 16 + li) * QPAD + ct * 16 + ch * 4;
    half4v o;
#pragma unroll
    for (int m = 0; m < 4; ++m) o[m] = (_Float16)aS[m];
    *(half4v*)&VS[wa] = o;
#pragma unroll
    for (int m = 0; m < 4; ++m) o[m] = (_Float16)aD[m];
    *(half4v*)&VD[wa] = o;
#pragma unroll
    for (int m = 0; m < 4; ++m) o[m] = (_Float16)aP[m];
    *(half4v*)&VP[wa] = o;
#pragma unroll
    for (int m = 0; m < 4; ++m) o[m] = (_Float16)aM[m];
    *(half4v*)&VM[wa] = o;
  }
  // no barrier: each wave reads back only the V rows it wrote (per-wave
  // DS ordering + compiler lgkmcnt on the same shared arrays)

  // ---- horizontal pass + SSIM ----
  float sum = 0.f;
#pragma unroll
  for (int jt = 0; jt < 4; ++jt) {
    const int ra = (w * 16 + li) * QPAD + jt * 16 + ch * 8;  // A: row=li, k-cols run
    const half8 vS = *(const half8*)&VS[ra];
    const half8 vD = *(const half8*)&VD[ra];
    const half8 vP = *(const half8*)&VP[ra];
    const half8 vM = *(const half8*)&VM[ra];
    f32x4 hS = __builtin_amdgcn_mfma_f32_16x16x32_f16(vS, band, z4, 0, 0, 0);
    f32x4 hD = __builtin_amdgcn_mfma_f32_16x16x32_f16(vD, band, z4, 0, 0, 0);
    f32x4 hP = __builtin_amdgcn_mfma_f32_16x16x32_f16(vP, band, z4, 0, 0, 0);
    f32x4 hM = __builtin_amdgcn_mfma_f32_16x16x32_f16(vM, band, z4, 0, 0, 0);
    // lane owns 4 px: out row = r0 + w*16 + ch*4 + m, col = c0 + jt*16 + li
#pragma unroll
    for (int m = 0; m < 4; ++m) {
      const float mp = hS[m], mm = hD[m];
      const float mp2 = mp * mp, mm2 = mm * mm;
      const float varP = hP[m] - mp2;
      const float varM = hM[m] - mm2;
      const float num1 = 0.5f * (mp2 - mm2) + C1F;
      const float den1 = 0.5f * (mp2 + mm2) + C1F;
      const float num2 = 0.5f * (varP - varM) + C2F;
      const float den2 = 0.5f * (varP + varM) + C2F;
      sum += __fdividef(num1 * num2, den1 * den2);
    }
  }

  // ---- deterministic block reduction ----
#pragma unroll
  for (int off = 32; off > 0; off >>= 1) sum += __shfl_down(sum, off, 64);
  if (lane == 0) psum[w] = sum;
  __syncthreads();
  if (tid == 0) partial[b] = psum[0] + psum[1] + psum[2] + psum[3];
}

extern "C" __global__ void ssim_reduce(const float* __restrict__ partial,
                                       float* __restrict__ out, int n, float scale) {
  __shared__ float sm[4];
  const int tid = threadIdx.x;
  float v = 0.f;
  for (int i = tid; i < n; i += 256) v += partial[i];
#pragma unroll
  for (int off = 32; off > 0; off >>= 1) v += __shfl_down(v, off, 64);
  if ((tid & 63) == 0) sm[tid >> 6] = v;
  __syncthreads();
  if (tid == 0) {
    out[0] = 1.0f - (sm[0] + sm[1] + sm[2] + sm[3]) * scale;
  }
}

extern "C" void kernel_launch(void* const* d_in, const int* in_sizes, int n_in,
                              void* d_out, int out_size, void* d_ws, size_t ws_size,
                              hipStream_t stream) {
  const float* Ii = (const float*)d_in[0];
  const float* Ir = (const float*)d_in[1];
  const float* win = (const float*)d_in[2];
  float* out = (float*)d_out;
  float* partial = (float*)d_ws;   // 6144 floats = 24.6 KB

  const int nblocks = 96 * 64;     // planes x (8x8 tiles of 64x64)
  ssim_main<<<dim3(nblocks), dim3(NT), 0, stream>>>(Ii, Ir, win, partial);
  ssim_reduce<<<dim3(1), dim3(256), 0, stream>>>(partial, out, nblocks,
                                                 1.0f / 25165824.0f);
}